// Round 10
// baseline (827.020 us; speedup 1.0000x reference)
//
#include <hip/hip_runtime.h>
#include <hip/hip_cooperative_groups.h>
#include <math.h>

namespace cg = cooperative_groups;

#define NN 50000
#define NNP 50048        // 391*128, padded row count for GEMM staging
#define NE 800000
#define NG 64
#define NBK 196          // buckets of 256 nodes
#define NCHK 1024        // edge chunks (= coop grid)
#define ECH2 782         // edges per chunk: 1024*782 >= 800000
#define TOT2 (NBK * NCHK)   // 200704
#define NSC 784          // scan chunks of 256: 784*256 = 200704
#define SWORK (NN * 32 + 163840)

typedef __attribute__((ext_vector_type(8))) __bf16 bf16x8;
typedef __attribute__((ext_vector_type(4))) float f32x4;

__device__ inline unsigned short f2bf(float f) {
    unsigned int u = __float_as_uint(f);
    u += 0x7fffu + ((u >> 16) & 1u);   // round-to-nearest-even
    return (unsigned short)(u >> 16);
}
__device__ inline float bflo(unsigned int v) { return __uint_as_float(v << 16); }
__device__ inline float bfhi(unsigned int v) { return __uint_as_float(v & 0xffff0000u); }
__device__ inline float bfs(unsigned short v) { return __uint_as_float((unsigned int)v << 16); }

#define GLD_LDS16(g, l)                                                          \
    __builtin_amdgcn_global_load_lds(                                            \
        (const __attribute__((address_space(1))) unsigned int*)(g),              \
        (__attribute__((address_space(3))) unsigned int*)(l), 16, 0, 0)

// ================= cooperative prep: setup + CSR build in ONE launch ============
__global__ __launch_bounds__(256) void prep_k(const float* __restrict__ x,
                                              const float* __restrict__ wr1,
                                              const float* __restrict__ wo1,
                                              const float* __restrict__ wr2,
                                              const float* __restrict__ wo2,
                                              const float* __restrict__ wr3,
                                              const float* __restrict__ wo3,
                                              const int* __restrict__ esrc,
                                              const int* __restrict__ edst,
                                              const int* __restrict__ batch,
                                              unsigned short* __restrict__ xb,
                                              unsigned short* __restrict__ W1T,
                                              unsigned short* __restrict__ W2T,
                                              unsigned short* __restrict__ W3T,
                                              int* __restrict__ H,
                                              int* __restrict__ S,
                                              int* __restrict__ hb,
                                              int* __restrict__ tmp,
                                              int* __restrict__ rowptr,
                                              int* __restrict__ colsrc,
                                              int* __restrict__ bounds,
                                              float* __restrict__ outp) {
    cg::grid_group grid = cg::this_grid();
    __shared__ int shm[768];
    const int t = threadIdx.x, bid = blockIdx.x;

    // ---- Phase A: x->bf16 + weight transposes + bounds + out-zero + histogram ----
    for (int id = bid * 256 + t; id < SWORK; id += NCHK * 256) {
        if (id < NN * 32) {
            float4 v = ((const float4*)x)[id];
            unsigned int p0 = ((unsigned int)f2bf(v.y) << 16) | f2bf(v.x);
            unsigned int p1 = ((unsigned int)f2bf(v.w) << 16) | f2bf(v.z);
            ((uint2*)xb)[id] = make_uint2(p0, p1);
        } else {
            int w = id - NN * 32;
            if (w < 32768) {
                int n = w >> 8, k = w & 255;
                W1T[w] = f2bf((k < 128) ? wr1[k * 128 + n] : wo1[(k - 128) * 128 + n]);
            } else if (w < 98304) {
                int j = w - 32768; int n = j >> 8, k = j & 255;
                W2T[j] = f2bf((k < 128) ? wr2[k * 256 + n] : wo2[(k - 128) * 256 + n]);
            } else {
                int j = w - 98304; int n = j >> 8, k = j & 255;
                W3T[j] = f2bf((n < 128) ? wr3[k * 128 + n] : wo3[k * 128 + (n - 128)]);
            }
        }
    }
    if (bid == 1) { for (int i = t; i < NG * 128; i += 256) outp[i] = 0.f; }
    if (bid == 2 && t <= NG) {
        int g = t, lo = 0, hi = NN;
        while (lo < hi) { int mid = (lo + hi) >> 1; if (batch[mid] < g) lo = mid + 1; else hi = mid; }
        bounds[g] = lo;
    }
    {   // histogram of chunk bid
        if (t < NBK) shm[t] = 0;
        __syncthreads();
        int e0 = bid * ECH2, e1 = min(NE, e0 + ECH2);
        for (int e = e0 + t; e < e1; e += 256) atomicAdd(&shm[edst[e] >> 8], 1);
        __syncthreads();
        if (t < NBK) H[t * NCHK + bid] = shm[t];       // bucket-major
    }
    grid.sync();

    // ---- Phase B1: per-scan-chunk sums ----
    for (int c = bid; c < NSC; c += NCHK) {
        int v = H[c * 256 + t];
        for (int off = 32; off; off >>= 1) v += __shfl_xor(v, off, 64);
        if ((t & 63) == 0) shm[t >> 6] = v;
        __syncthreads();
        if (t == 0) hb[c] = shm[0] + shm[1] + shm[2] + shm[3];
        __syncthreads();
    }
    grid.sync();

    // ---- Phase B2: block 0 exclusive-scans the NSC chunk sums ----
    if (bid == 0) {
        int v[4], tsum = 0;
        for (int i = 0; i < 4; ++i) { int c = t * 4 + i; v[i] = (c < NSC) ? hb[c] : 0; tsum += v[i]; }
        shm[t] = tsum; __syncthreads();
        for (int off = 1; off < 256; off <<= 1) {
            int u = (t >= off) ? shm[t - off] : 0;
            __syncthreads(); shm[t] += u; __syncthreads();
        }
        int run = shm[t] - tsum;
        for (int i = 0; i < 4; ++i) { int c = t * 4 + i; if (c < NSC) { hb[c] = run; run += v[i]; } }
    }
    grid.sync();

    // ---- Phase B3: local scan + chunk offset -> S ----
    for (int c = bid; c < NSC; c += NCHK) {
        int v = H[c * 256 + t];
        shm[t] = v; __syncthreads();
        for (int off = 1; off < 256; off <<= 1) {
            int u = (t >= off) ? shm[t - off] : 0;
            __syncthreads(); shm[t] += u; __syncthreads();
        }
        S[c * 256 + t] = hb[c] + shm[t] - v;
        __syncthreads();
    }
    grid.sync();

    // ---- Phase C: scatter edges to bucket-major tmp (private regions) ----
    {
        if (t < NBK) shm[t] = S[t * NCHK + bid];
        __syncthreads();
        int e0 = bid * ECH2, e1 = min(NE, e0 + ECH2);
        for (int e = e0 + t; e < e1; e += 256) {
            int d = edst[e];
            int p = atomicAdd(&shm[d >> 8], 1);
            tmp[p] = ((d & 255) << 16) | esrc[e];
        }
    }
    grid.sync();

    // ---- Phase D: per-bucket node sort -> rowptr + colsrc ----
    if (bid < NBK) {
        int* hist = shm; int* off = shm + 256; int* cur = shm + 512;
        int base = S[bid * NCHK];
        int next = (bid < NBK - 1) ? S[(bid + 1) * NCHK] : NE;
        int cntb = next - base;
        hist[t] = 0;
        __syncthreads();
        for (int i = t; i < cntb; i += 256) atomicAdd(&hist[tmp[base + i] >> 16], 1);
        __syncthreads();
        int v = hist[t];
        off[t] = v; __syncthreads();
        for (int o = 1; o < 256; o <<= 1) {
            int u = (t >= o) ? off[t - o] : 0;
            __syncthreads(); off[t] += u; __syncthreads();
        }
        int excl = off[t] - v;
        int node = bid * 256 + t;
        if (node <= NN) rowptr[node] = base + excl;
        cur[t] = excl;
        __syncthreads();
        for (int i = t; i < cntb; i += 256) {
            int e = tmp[base + i];
            int p = atomicAdd(&cur[e >> 16], 1);
            colsrc[base + p] = e & 0xffff;
        }
    }
}

// ---------------- edge aggregation, bf16 features, 8-way MLP ----------------
__global__ __launch_bounds__(256) void aggb_k(const unsigned short* __restrict__ feat,
                                              const int* __restrict__ rowptr,
                                              const int* __restrict__ colsrc,
                                              unsigned short* __restrict__ outp) {
    int node = __builtin_amdgcn_readfirstlane((int)(blockIdx.x * 4 + (threadIdx.x >> 6)));
    int lane = threadIdx.x & 63;
    int beg = rowptr[node], end = rowptr[node + 1];
    float ax = 0.f, ay = 0.f;
    int e = beg;
    for (; e + 8 <= end; e += 8) {
        unsigned int v[8];
#pragma unroll
        for (int i = 0; i < 8; ++i)
            v[i] = *(const unsigned int*)&feat[(size_t)colsrc[e + i] * 128 + lane * 2];
#pragma unroll
        for (int i = 0; i < 8; ++i) { ax += bflo(v[i]); ay += bfhi(v[i]); }
    }
    for (; e < end; ++e) {
        unsigned int v0 = *(const unsigned int*)&feat[(size_t)colsrc[e] * 128 + lane * 2];
        ax += bflo(v0); ay += bfhi(v0);
    }
    unsigned int p = ((unsigned int)f2bf(ay) << 16) | f2bf(ax);
    *(unsigned int*)&outp[(size_t)node * 128 + lane * 2] = p;
}

// fused L3 epilogue: v = elu(agg(y)[n] + r[n] + b3) per node (aggb structure)
__global__ __launch_bounds__(256) void aggf_k(const unsigned short* __restrict__ y,
                                              const unsigned short* __restrict__ rr,
                                              const float* __restrict__ b3,
                                              const int* __restrict__ rowptr,
                                              const int* __restrict__ colsrc,
                                              unsigned short* __restrict__ outp) {
    int node = __builtin_amdgcn_readfirstlane((int)(blockIdx.x * 4 + (threadIdx.x >> 6)));
    int lane = threadIdx.x & 63;
    int beg = rowptr[node], end = rowptr[node + 1];
    float ax = 0.f, ay = 0.f;
    int e = beg;
    for (; e + 8 <= end; e += 8) {
        unsigned int v[8];
#pragma unroll
        for (int i = 0; i < 8; ++i)
            v[i] = *(const unsigned int*)&y[(size_t)colsrc[e + i] * 128 + lane * 2];
#pragma unroll
        for (int i = 0; i < 8; ++i) { ax += bflo(v[i]); ay += bfhi(v[i]); }
    }
    for (; e < end; ++e) {
        unsigned int v0 = *(const unsigned int*)&y[(size_t)colsrc[e] * 128 + lane * 2];
        ax += bflo(v0); ay += bfhi(v0);
    }
    unsigned int rv = *(const unsigned int*)&rr[(size_t)node * 128 + lane * 2];
    float2 bb = *(const float2*)&b3[lane * 2];
    float vx = ax + bflo(rv) + bb.x;
    float vy = ay + bfhi(rv) + bb.y;
    vx = vx > 0.f ? vx : (__expf(vx) - 1.f);
    vy = vy > 0.f ? vy : (__expf(vy) - 1.f);
    unsigned int p = ((unsigned int)f2bf(vy) << 16) | f2bf(vx);
    *(unsigned int*)&outp[(size_t)node * 128 + lane * 2] = p;
}

// ---------------- 64x128 MFMA GEMM (L1) ----------------
template <int MT, int KA, int N, bool TWO, bool BIAS, bool ELU>
__global__ __launch_bounds__(256) void gemm_k(const unsigned short* __restrict__ A1,
                                              const unsigned short* __restrict__ A2,
                                              const unsigned short* __restrict__ WT,
                                              const float* __restrict__ bias,
                                              unsigned short* __restrict__ Cout) {
    constexpr int KTOT = TWO ? 2 * KA : KA;
    constexpr int MI = MT / 32;
    __shared__ __attribute__((aligned(16))) unsigned short As[MT * 32];
    __shared__ __attribute__((aligned(16))) unsigned short Bs[128 * 32];
    const int t = threadIdx.x;
    const int wv = t >> 6, lane = t & 63;
    const int qd = lane >> 4, l16 = lane & 15;
    const int m0 = blockIdx.x * MT, n0 = 0;
    const int mh = (wv & 1) * (MT / 2), nh = (wv >> 1) * 64;
    const int srow = lane >> 2;
    const int skk  = (lane & 3) * 8;

    f32x4 acc[MI][4] = {};

    for (int k0 = 0; k0 < KTOT; k0 += 32) {
        const unsigned short* Abase = (TWO && k0 >= KA) ? (A2 + (k0 - KA)) : (A1 + k0);
#pragma unroll
        for (int i = 0; i < MT / 64; ++i) {
            int chunk = wv * (MT / 64) + i;
            const unsigned short* g = Abase + (size_t)(m0 + chunk * 16 + srow) * KA + skk;
            GLD_LDS16(g, &As[chunk * 512]);
        }
        const unsigned short* Wbase = WT + k0;
#pragma unroll
        for (int i = 0; i < 2; ++i) {
            int chunk = wv * 2 + i;
            const unsigned short* g = Wbase + (size_t)(n0 + chunk * 16 + srow) * KTOT + skk;
            GLD_LDS16(g, &Bs[chunk * 512]);
        }
        __syncthreads();
        bf16x8 af[MI], bfr[4];
#pragma unroll
        for (int mi = 0; mi < MI; ++mi)
            af[mi] = *(const bf16x8*)&As[(mh + mi * 16 + l16) * 32 + qd * 8];
#pragma unroll
        for (int ni = 0; ni < 4; ++ni)
            bfr[ni] = *(const bf16x8*)&Bs[(nh + ni * 16 + l16) * 32 + qd * 8];
#pragma unroll
        for (int mi = 0; mi < MI; ++mi)
#pragma unroll
            for (int ni = 0; ni < 4; ++ni)
                acc[mi][ni] = __builtin_amdgcn_mfma_f32_16x16x32_bf16(
                    af[mi], bfr[ni], acc[mi][ni], 0, 0, 0);
        __syncthreads();
    }

#pragma unroll
    for (int mi = 0; mi < MI; ++mi)
#pragma unroll
        for (int ni = 0; ni < 4; ++ni)
#pragma unroll
            for (int r = 0; r < 4; ++r) {
                int mm = m0 + mh + mi * 16 + qd * 4 + r;
                if (mm < NN) {
                    int nn = n0 + nh + ni * 16 + l16;
                    float v = acc[mi][ni][r];
                    if (BIAS) v += bias[nn];
                    if (ELU) v = v > 0.f ? v : (__expf(v) - 1.f);
                    Cout[(size_t)mm * N + nn] = f2bf(v);
                }
            }
}

// ---------------- 64x256 single-pass GEMM (L2 / L3): A read once ----------------
template <int KA, bool TWO, bool BIAS, bool ELU, bool SPLIT>
__global__ __launch_bounds__(256) void gemm256_k(const unsigned short* __restrict__ A1,
                                                 const unsigned short* __restrict__ A2,
                                                 const unsigned short* __restrict__ WT,
                                                 const float* __restrict__ bias,
                                                 unsigned short* __restrict__ Cout,
                                                 unsigned short* __restrict__ Cout2) {
    constexpr int KTOT = TWO ? 2 * KA : KA;
    __shared__ __attribute__((aligned(16))) unsigned short As[64 * 32];
    __shared__ __attribute__((aligned(16))) unsigned short Bs[256 * 32];
    const int t = threadIdx.x;
    const int wv = t >> 6, lane = t & 63;
    const int qd = lane >> 4, l16 = lane & 15;
    const int m0 = blockIdx.x * 64;
    const int srow = lane >> 2;
    const int skk  = (lane & 3) * 8;

    f32x4 acc[4][4] = {};

    for (int k0 = 0; k0 < KTOT; k0 += 32) {
        const unsigned short* Abase = (TWO && k0 >= KA) ? (A2 + (k0 - KA)) : (A1 + k0);
        {   // A: 4 chunks of 16 rows, one per wave
            const unsigned short* g = Abase + (size_t)(m0 + wv * 16 + srow) * KA + skk;
            GLD_LDS16(g, &As[wv * 512]);
        }
        const unsigned short* Wbase = WT + k0;
#pragma unroll
        for (int i = 0; i < 4; ++i) {     // B: 16 chunks, 4 per wave
            int chunk = wv * 4 + i;
            const unsigned short* g = Wbase + (size_t)(chunk * 16 + srow) * KTOT + skk;
            GLD_LDS16(g, &Bs[chunk * 512]);
        }
        __syncthreads();
        bf16x8 af[4], bfr[4];
#pragma unroll
        for (int mi = 0; mi < 4; ++mi)
            af[mi] = *(const bf16x8*)&As[(mi * 16 + l16) * 32 + qd * 8];
#pragma unroll
        for (int ni = 0; ni < 4; ++ni)
            bfr[ni] = *(const bf16x8*)&Bs[(wv * 64 + ni * 16 + l16) * 32 + qd * 8];
#pragma unroll
        for (int mi = 0; mi < 4; ++mi)
#pragma unroll
            for (int ni = 0; ni < 4; ++ni)
                acc[mi][ni] = __builtin_amdgcn_mfma_f32_16x16x32_bf16(
                    af[mi], bfr[ni], acc[mi][ni], 0, 0, 0);
        __syncthreads();
    }

#pragma unroll
    for (int mi = 0; mi < 4; ++mi)
#pragma unroll
        for (int ni = 0; ni < 4; ++ni)
#pragma unroll
            for (int r = 0; r < 4; ++r) {
                int mm = m0 + mi * 16 + qd * 4 + r;
                if (mm < NN) {
                    int nn = wv * 64 + ni * 16 + l16;
                    float v = acc[mi][ni][r];
                    if (BIAS) v += bias[nn];
                    if (ELU) v = v > 0.f ? v : (__expf(v) - 1.f);
                    unsigned short b = f2bf(v);
                    if (SPLIT) {
                        unsigned short* dst = (nn < 128) ? Cout : Cout2;
                        dst[(size_t)mm * 128 + (nn & 127)] = b;
                    } else {
                        Cout[(size_t)mm * 256 + nn] = b;
                    }
                }
            }
}

// ---------------- segmented graph-sum + divide ----------------
__global__ __launch_bounds__(128) void sum_k(const unsigned short* __restrict__ vals,
                                             const int* __restrict__ batch,
                                             float* __restrict__ outsum) {
    const int CH = 25;                        // 2000 * 25 = 50000
    int n0 = blockIdx.x * CH;
    int c = threadIdx.x;
    int g = batch[n0];
    float acc = 0.f;
    for (int i = 0; i < CH; ++i) {
        int n = n0 + i;
        int gn = batch[n];
        if (gn != g) {
            unsafeAtomicAdd(&outsum[(size_t)g * 128 + c], acc);
            acc = 0.f; g = gn;
        }
        acc += bfs(vals[(size_t)n * 128 + c]);
    }
    unsafeAtomicAdd(&outsum[(size_t)g * 128 + c], acc);
}

__global__ void divide_k(const int* __restrict__ bounds, float* __restrict__ out) {
    int i = blockIdx.x * 256 + threadIdx.x;
    if (i < NG * 128) {
        int g = i >> 7;
        float c = (float)(bounds[g + 1] - bounds[g]);
        out[i] /= fmaxf(c, 1.f);
    }
}

extern "C" void kernel_launch(void* const* d_in, const int* in_sizes, int n_in,
                              void* d_out, int out_size, void* d_ws, size_t ws_size,
                              hipStream_t stream) {
    const float* x       = (const float*)d_in[0];
    const int*   ei      = (const int*)d_in[1];
    const int*   batch   = (const int*)d_in[2];
    const float* w_rel1  = (const float*)d_in[3];
    const float* b_rel1  = (const float*)d_in[4];
    const float* w_root1 = (const float*)d_in[5];
    const float* w_rel2  = (const float*)d_in[6];
    const float* b_rel2  = (const float*)d_in[7];
    const float* w_root2 = (const float*)d_in[8];
    const float* w_rel3  = (const float*)d_in[9];
    const float* b_rel3  = (const float*)d_in[10];
    const float* w_root3 = (const float*)d_in[11];
    const int* esrc = ei;
    const int* edst = ei + NE;

    unsigned short* Ab = (unsigned short*)d_ws;          // [NNP,128] agg out / y
    unsigned short* Bb = Ab + (size_t)NNP * 128;         // [NNP,128] h1 / r
    unsigned short* Cb = Bb + (size_t)NNP * 128;         // [NNP,256] h2 ; front = node vals
    unsigned short* xb = Cb + (size_t)NNP * 256;         // [NNP,128] x in bf16
    unsigned short* W1T = xb + (size_t)NNP * 128;        // [128,256]
    unsigned short* W2T = W1T + 128 * 256;               // [256,256]
    unsigned short* W3T = W2T + 256 * 256;               // [256,256]
    int* rowptr = (int*)(W3T + 256 * 256);               // NN+1
    int* colsrc = rowptr + (NN + 1);                     // NE
    int* tmp    = colsrc + NE;                           // NE
    int* H      = tmp + NE;                              // TOT2
    int* S      = H + TOT2;                              // TOT2
    int* hb     = S + TOT2;                              // 1024
    int* bounds = hb + 1024;                             // NG+1
    float* outp = (float*)d_out;

    // --- one cooperative launch: setup + bounds/zero + CSR build ---
    void* args[] = {(void*)&x, (void*)&w_rel1, (void*)&w_root1, (void*)&w_rel2,
                    (void*)&w_root2, (void*)&w_rel3, (void*)&w_root3,
                    (void*)&esrc, (void*)&edst, (void*)&batch,
                    (void*)&xb, (void*)&W1T, (void*)&W2T, (void*)&W3T,
                    (void*)&H, (void*)&S, (void*)&hb, (void*)&tmp,
                    (void*)&rowptr, (void*)&colsrc, (void*)&bounds, (void*)&outp};
    hipLaunchCooperativeKernel((void*)prep_k, dim3(NCHK), dim3(256), args, 0, stream);

    // L1: h1 = elu([agg(x) | x] @ W1 + b1)    -> Bb
    aggb_k<<<NN / 4, 256, 0, stream>>>(xb, rowptr, colsrc, Ab);
    gemm_k<64, 128, 128, true, true, true>
        <<<NNP / 64, 256, 0, stream>>>(Ab, xb, W1T, b_rel1, Bb);

    // L2: h2 = elu([agg(h1) | h1] @ W2 + b2)  -> Cb   (single-pass N=256)
    aggb_k<<<NN / 4, 256, 0, stream>>>(Bb, rowptr, colsrc, Ab);
    gemm256_k<128, true, true, true, false>
        <<<NNP / 64, 256, 0, stream>>>(Ab, Bb, W2T, b_rel2, Cb, nullptr);

    // L3: y = h2@w_rel3 -> Ab, r = h2@w_root3 -> Bb (one dispatch, split outputs)
    gemm256_k<256, false, false, false, true>
        <<<NNP / 64, 256, 0, stream>>>(Cb, nullptr, W3T, nullptr, Ab, Bb);

    // fused gather+elu per node, then segmented graph-mean
    aggf_k<<<NN / 4, 256, 0, stream>>>(Ab, Bb, b_rel3, rowptr, colsrc, Cb);
    sum_k<<<NN / 25, 128, 0, stream>>>(Cb, batch, outp);
    divide_k<<<(NG * 128 + 255) / 256, 256, 0, stream>>>(bounds, outp);
}

// Round 11
// 308.654 us; speedup vs baseline: 2.6794x; 2.6794x over previous
//
#include <hip/hip_runtime.h>
#include <math.h>

#define NN 50000
#define NNP 50048        // 391*128, padded row count for GEMM staging
#define NE 800000
#define NG 64
#define NBK 196          // buckets of 256 nodes
#define ECH 4082         // edges per hist/scatter block
#define TOTH (NBK * NBK) // 38416
#define NBH 151          // ceil(TOTH/256)

typedef __attribute__((ext_vector_type(8))) __bf16 bf16x8;
typedef __attribute__((ext_vector_type(4))) float f32x4;

__device__ inline unsigned short f2bf(float f) {
    unsigned int u = __float_as_uint(f);
    u += 0x7fffu + ((u >> 16) & 1u);   // round-to-nearest-even
    return (unsigned short)(u >> 16);
}
__device__ inline float bflo(unsigned int v) { return __uint_as_float(v << 16); }
__device__ inline float bfhi(unsigned int v) { return __uint_as_float(v & 0xffff0000u); }
__device__ inline float bfs(unsigned short v) { return __uint_as_float((unsigned int)v << 16); }

#define GLD_LDS16(g, l)                                                          \
    __builtin_amdgcn_global_load_lds(                                            \
        (const __attribute__((address_space(1))) unsigned int*)(g),              \
        (__attribute__((address_space(3))) unsigned int*)(l), 16, 0, 0)

// ---------------- setup: x fp32->bf16 + weight transposes ----------------
__global__ __launch_bounds__(256) void setup_k(const float* __restrict__ x,
                                               const float* __restrict__ wr1,
                                               const float* __restrict__ wo1,
                                               const float* __restrict__ wr2,
                                               const float* __restrict__ wo2,
                                               const float* __restrict__ wr3,
                                               const float* __restrict__ wo3,
                                               unsigned short* __restrict__ xb,
                                               unsigned short* __restrict__ W1T,
                                               unsigned short* __restrict__ W2T,
                                               unsigned short* __restrict__ W3T) {
    int id = blockIdx.x * 256 + threadIdx.x;
    if (id < NN * 32) {                       // x: 4 floats per thread
        float4 v = ((const float4*)x)[id];
        unsigned int p0 = ((unsigned int)f2bf(v.y) << 16) | f2bf(v.x);
        unsigned int p1 = ((unsigned int)f2bf(v.w) << 16) | f2bf(v.z);
        ((uint2*)xb)[id] = make_uint2(p0, p1);
        return;
    }
    int w = id - NN * 32;
    if (w < 32768) {
        int n = w >> 8, k = w & 255;
        W1T[w] = f2bf((k < 128) ? wr1[k * 128 + n] : wo1[(k - 128) * 128 + n]);
    } else if (w < 98304) {
        int j = w - 32768; int n = j >> 8, k = j & 255;
        W2T[j] = f2bf((k < 128) ? wr2[k * 256 + n] : wo2[(k - 128) * 256 + n]);
    } else if (w < 163840) {
        int j = w - 98304; int n = j >> 8, k = j & 255;
        W3T[j] = f2bf((n < 128) ? wr3[k * 128 + n] : wo3[k * 128 + (n - 128)]);
    }
}

// ---------------- CSR build: block-private counting sort ----------------
__global__ __launch_bounds__(256) void hist_k(const int* __restrict__ dst,
                                              int* __restrict__ H) {
    __shared__ int h[NBK];
    int t = threadIdx.x, k = blockIdx.x;
    if (t < NBK) h[t] = 0;
    __syncthreads();
    int e0 = k * ECH, e1 = min(NE, e0 + ECH);
    for (int e = e0 + t; e < e1; e += 256) atomicAdd(&h[dst[e] >> 8], 1);
    __syncthreads();
    if (t < NBK) H[t * NBK + k] = h[t];          // bucket-major layout
}

__global__ __launch_bounds__(256) void hsum_k(const int* __restrict__ H,
                                              int* __restrict__ hb) {
    int i = blockIdx.x * 256 + threadIdx.x;
    int v = (i < TOTH) ? H[i] : 0;
    for (int off = 32; off; off >>= 1) v += __shfl_xor(v, off, 64);
    __shared__ int ws[4];
    if ((threadIdx.x & 63) == 0) ws[threadIdx.x >> 6] = v;
    __syncthreads();
    if (threadIdx.x == 0) hb[blockIdx.x] = ws[0] + ws[1] + ws[2] + ws[3];
}

__global__ __launch_bounds__(256) void hscan_k(const int* __restrict__ hb,
                                               int* __restrict__ hoff) {
    __shared__ int s[256];
    int t = threadIdx.x;
    int v = (t < NBH) ? hb[t] : 0;
    s[t] = v; __syncthreads();
    for (int off = 1; off < 256; off <<= 1) {
        int u = (t >= off) ? s[t - off] : 0;
        __syncthreads(); s[t] += u; __syncthreads();
    }
    hoff[t] = (t == 0) ? 0 : s[t - 1];
}

__global__ __launch_bounds__(256) void happly_k(const int* __restrict__ H,
                                                const int* __restrict__ hoff,
                                                int* __restrict__ S) {
    int t = threadIdx.x;
    int i = blockIdx.x * 256 + t;
    int v = (i < TOTH) ? H[i] : 0;
    __shared__ int s[256];
    s[t] = v; __syncthreads();
    for (int off = 1; off < 256; off <<= 1) {
        int u = (t >= off) ? s[t - off] : 0;
        __syncthreads(); s[t] += u; __syncthreads();
    }
    if (i < TOTH) S[i] = hoff[blockIdx.x] + s[t] - v;
}

__global__ __launch_bounds__(256) void scatter_k(const int* __restrict__ src,
                                                 const int* __restrict__ dst,
                                                 const int* __restrict__ S,
                                                 int* __restrict__ tmp) {
    __shared__ int cur[NBK];
    int t = threadIdx.x, k = blockIdx.x;
    if (t < NBK) cur[t] = S[t * NBK + k];
    __syncthreads();
    int e0 = k * ECH, e1 = min(NE, e0 + ECH);
    for (int e = e0 + t; e < e1; e += 256) {
        int d = dst[e];
        int p = atomicAdd(&cur[d >> 8], 1);
        tmp[p] = ((d & 255) << 16) | src[e];
    }
}

__global__ __launch_bounds__(256) void csr_k(const int* __restrict__ tmp,
                                             const int* __restrict__ S,
                                             int* __restrict__ rowptr,
                                             int* __restrict__ colsrc) {
    __shared__ int hist[256], off[256], cur[256];
    int t = threadIdx.x, b = blockIdx.x;
    int base = S[b * NBK];
    int next = (b < NBK - 1) ? S[(b + 1) * NBK] : NE;
    int cntb = next - base;
    hist[t] = 0;
    __syncthreads();
    for (int i = t; i < cntb; i += 256) atomicAdd(&hist[tmp[base + i] >> 16], 1);
    __syncthreads();
    int v = hist[t];
    off[t] = v; __syncthreads();
    for (int o = 1; o < 256; o <<= 1) {
        int u = (t >= o) ? off[t - o] : 0;
        __syncthreads(); off[t] += u; __syncthreads();
    }
    int excl = off[t] - v;
    int node = b * 256 + t;
    if (node <= NN) rowptr[node] = base + excl;
    cur[t] = excl;
    __syncthreads();
    for (int i = t; i < cntb; i += 256) {
        int e = tmp[base + i];
        int p = atomicAdd(&cur[e >> 16], 1);
        colsrc[base + p] = e & 0xffff;
    }
}

// ---------------- edge aggregation, bf16 features, 8-way MLP ----------------
__global__ __launch_bounds__(256) void aggb_k(const unsigned short* __restrict__ feat,
                                              const int* __restrict__ rowptr,
                                              const int* __restrict__ colsrc,
                                              unsigned short* __restrict__ outp) {
    int node = __builtin_amdgcn_readfirstlane((int)(blockIdx.x * 4 + (threadIdx.x >> 6)));
    int lane = threadIdx.x & 63;
    int beg = rowptr[node], end = rowptr[node + 1];
    float ax = 0.f, ay = 0.f;
    int e = beg;
    for (; e + 8 <= end; e += 8) {
        unsigned int v[8];
#pragma unroll
        for (int i = 0; i < 8; ++i)
            v[i] = *(const unsigned int*)&feat[(size_t)colsrc[e + i] * 128 + lane * 2];
#pragma unroll
        for (int i = 0; i < 8; ++i) { ax += bflo(v[i]); ay += bfhi(v[i]); }
    }
    for (; e < end; ++e) {
        unsigned int v0 = *(const unsigned int*)&feat[(size_t)colsrc[e] * 128 + lane * 2];
        ax += bflo(v0); ay += bfhi(v0);
    }
    unsigned int p = ((unsigned int)f2bf(ay) << 16) | f2bf(ax);
    *(unsigned int*)&outp[(size_t)node * 128 + lane * 2] = p;
}

// fused L3 epilogue: v = elu(agg(y)[n] + r[n] + b3) per node (aggb structure)
__global__ __launch_bounds__(256) void aggf_k(const unsigned short* __restrict__ y,
                                              const unsigned short* __restrict__ rr,
                                              const float* __restrict__ b3,
                                              const int* __restrict__ rowptr,
                                              const int* __restrict__ colsrc,
                                              unsigned short* __restrict__ outp) {
    int node = __builtin_amdgcn_readfirstlane((int)(blockIdx.x * 4 + (threadIdx.x >> 6)));
    int lane = threadIdx.x & 63;
    int beg = rowptr[node], end = rowptr[node + 1];
    float ax = 0.f, ay = 0.f;
    int e = beg;
    for (; e + 8 <= end; e += 8) {
        unsigned int v[8];
#pragma unroll
        for (int i = 0; i < 8; ++i)
            v[i] = *(const unsigned int*)&y[(size_t)colsrc[e + i] * 128 + lane * 2];
#pragma unroll
        for (int i = 0; i < 8; ++i) { ax += bflo(v[i]); ay += bfhi(v[i]); }
    }
    for (; e < end; ++e) {
        unsigned int v0 = *(const unsigned int*)&y[(size_t)colsrc[e] * 128 + lane * 2];
        ax += bflo(v0); ay += bfhi(v0);
    }
    unsigned int rv = *(const unsigned int*)&rr[(size_t)node * 128 + lane * 2];
    float2 bb = *(const float2*)&b3[lane * 2];
    float vx = ax + bflo(rv) + bb.x;
    float vy = ay + bfhi(rv) + bb.y;
    vx = vx > 0.f ? vx : (__expf(vx) - 1.f);
    vy = vy > 0.f ? vy : (__expf(vy) - 1.f);
    unsigned int p = ((unsigned int)f2bf(vy) << 16) | f2bf(vx);
    *(unsigned int*)&outp[(size_t)node * 128 + lane * 2] = p;
}

// ---------------- 64x128 MFMA GEMM (L1) ----------------
template <int MT, int KA, int N, bool TWO, bool BIAS, bool ELU>
__global__ __launch_bounds__(256) void gemm_k(const unsigned short* __restrict__ A1,
                                              const unsigned short* __restrict__ A2,
                                              const unsigned short* __restrict__ WT,
                                              const float* __restrict__ bias,
                                              unsigned short* __restrict__ Cout) {
    constexpr int KTOT = TWO ? 2 * KA : KA;
    constexpr int MI = MT / 32;
    __shared__ __attribute__((aligned(16))) unsigned short As[MT * 32];
    __shared__ __attribute__((aligned(16))) unsigned short Bs[128 * 32];
    const int t = threadIdx.x;
    const int wv = t >> 6, lane = t & 63;
    const int qd = lane >> 4, l16 = lane & 15;
    const int m0 = blockIdx.x * MT, n0 = 0;
    const int mh = (wv & 1) * (MT / 2), nh = (wv >> 1) * 64;
    const int srow = lane >> 2;
    const int skk  = (lane & 3) * 8;

    f32x4 acc[MI][4] = {};

    for (int k0 = 0; k0 < KTOT; k0 += 32) {
        const unsigned short* Abase = (TWO && k0 >= KA) ? (A2 + (k0 - KA)) : (A1 + k0);
#pragma unroll
        for (int i = 0; i < MT / 64; ++i) {
            int chunk = wv * (MT / 64) + i;
            const unsigned short* g = Abase + (size_t)(m0 + chunk * 16 + srow) * KA + skk;
            GLD_LDS16(g, &As[chunk * 512]);
        }
        const unsigned short* Wbase = WT + k0;
#pragma unroll
        for (int i = 0; i < 2; ++i) {
            int chunk = wv * 2 + i;
            const unsigned short* g = Wbase + (size_t)(n0 + chunk * 16 + srow) * KTOT + skk;
            GLD_LDS16(g, &Bs[chunk * 512]);
        }
        __syncthreads();
        bf16x8 af[MI], bfr[4];
#pragma unroll
        for (int mi = 0; mi < MI; ++mi)
            af[mi] = *(const bf16x8*)&As[(mh + mi * 16 + l16) * 32 + qd * 8];
#pragma unroll
        for (int ni = 0; ni < 4; ++ni)
            bfr[ni] = *(const bf16x8*)&Bs[(nh + ni * 16 + l16) * 32 + qd * 8];
#pragma unroll
        for (int mi = 0; mi < MI; ++mi)
#pragma unroll
            for (int ni = 0; ni < 4; ++ni)
                acc[mi][ni] = __builtin_amdgcn_mfma_f32_16x16x32_bf16(
                    af[mi], bfr[ni], acc[mi][ni], 0, 0, 0);
        __syncthreads();
    }

#pragma unroll
    for (int mi = 0; mi < MI; ++mi)
#pragma unroll
        for (int ni = 0; ni < 4; ++ni)
#pragma unroll
            for (int r = 0; r < 4; ++r) {
                int mm = m0 + mh + mi * 16 + qd * 4 + r;
                if (mm < NN) {
                    int nn = n0 + nh + ni * 16 + l16;
                    float v = acc[mi][ni][r];
                    if (BIAS) v += bias[nn];
                    if (ELU) v = v > 0.f ? v : (__expf(v) - 1.f);
                    Cout[(size_t)mm * N + nn] = f2bf(v);
                }
            }
}

// ---------------- 64x256 single-pass GEMM (L2 / L3): A read once ----------------
template <int KA, bool TWO, bool BIAS, bool ELU, bool SPLIT>
__global__ __launch_bounds__(256) void gemm256_k(const unsigned short* __restrict__ A1,
                                                 const unsigned short* __restrict__ A2,
                                                 const unsigned short* __restrict__ WT,
                                                 const float* __restrict__ bias,
                                                 unsigned short* __restrict__ Cout,
                                                 unsigned short* __restrict__ Cout2) {
    constexpr int KTOT = TWO ? 2 * KA : KA;
    __shared__ __attribute__((aligned(16))) unsigned short As[64 * 32];
    __shared__ __attribute__((aligned(16))) unsigned short Bs[256 * 32];
    const int t = threadIdx.x;
    const int wv = t >> 6, lane = t & 63;
    const int qd = lane >> 4, l16 = lane & 15;
    const int m0 = blockIdx.x * 64;
    const int srow = lane >> 2;
    const int skk  = (lane & 3) * 8;

    f32x4 acc[4][4] = {};

    for (int k0 = 0; k0 < KTOT; k0 += 32) {
        const unsigned short* Abase = (TWO && k0 >= KA) ? (A2 + (k0 - KA)) : (A1 + k0);
        {   // A: 4 chunks of 16 rows, one per wave
            const unsigned short* g = Abase + (size_t)(m0 + wv * 16 + srow) * KA + skk;
            GLD_LDS16(g, &As[wv * 512]);
        }
        const unsigned short* Wbase = WT + k0;
#pragma unroll
        for (int i = 0; i < 4; ++i) {     // B: 16 chunks, 4 per wave
            int chunk = wv * 4 + i;
            const unsigned short* g = Wbase + (size_t)(chunk * 16 + srow) * KTOT + skk;
            GLD_LDS16(g, &Bs[chunk * 512]);
        }
        __syncthreads();
        bf16x8 af[4], bfr[4];
#pragma unroll
        for (int mi = 0; mi < 4; ++mi)
            af[mi] = *(const bf16x8*)&As[(mi * 16 + l16) * 32 + qd * 8];
#pragma unroll
        for (int ni = 0; ni < 4; ++ni)
            bfr[ni] = *(const bf16x8*)&Bs[(wv * 64 + ni * 16 + l16) * 32 + qd * 8];
#pragma unroll
        for (int mi = 0; mi < 4; ++mi)
#pragma unroll
            for (int ni = 0; ni < 4; ++ni)
                acc[mi][ni] = __builtin_amdgcn_mfma_f32_16x16x32_bf16(
                    af[mi], bfr[ni], acc[mi][ni], 0, 0, 0);
        __syncthreads();
    }

#pragma unroll
    for (int mi = 0; mi < 4; ++mi)
#pragma unroll
        for (int ni = 0; ni < 4; ++ni)
#pragma unroll
            for (int r = 0; r < 4; ++r) {
                int mm = m0 + mi * 16 + qd * 4 + r;
                if (mm < NN) {
                    int nn = wv * 64 + ni * 16 + l16;
                    float v = acc[mi][ni][r];
                    if (BIAS) v += bias[nn];
                    if (ELU) v = v > 0.f ? v : (__expf(v) - 1.f);
                    unsigned short b = f2bf(v);
                    if (SPLIT) {
                        unsigned short* dst = (nn < 128) ? Cout : Cout2;
                        dst[(size_t)mm * 128 + (nn & 127)] = b;
                    } else {
                        Cout[(size_t)mm * 256 + nn] = b;
                    }
                }
            }
}

// ---------------- epilogue ----------------
__global__ __launch_bounds__(128) void bounds_k(const int* __restrict__ batch,
                                                int* __restrict__ bounds,
                                                float* __restrict__ outp) {
    int g = threadIdx.x;
    if (g <= NG) {
        int lo = 0, hi = NN;
        while (lo < hi) {
            int mid = (lo + hi) >> 1;
            if (batch[mid] < g) lo = mid + 1; else hi = mid;
        }
        bounds[g] = lo;
    }
    for (int i = threadIdx.x; i < NG * 128; i += 128) outp[i] = 0.f;
}

// segmented graph-sum of per-node bf16 values (batch sorted).
__global__ __launch_bounds__(128) void sum_k(const unsigned short* __restrict__ vals,
                                             const int* __restrict__ batch,
                                             float* __restrict__ outsum) {
    const int CH = 25;                        // 2000 * 25 = 50000
    int n0 = blockIdx.x * CH;
    int c = threadIdx.x;
    int g = batch[n0];
    float acc = 0.f;
    for (int i = 0; i < CH; ++i) {
        int n = n0 + i;
        int gn = batch[n];
        if (gn != g) {
            unsafeAtomicAdd(&outsum[(size_t)g * 128 + c], acc);
            acc = 0.f; g = gn;
        }
        acc += bfs(vals[(size_t)n * 128 + c]);
    }
    unsafeAtomicAdd(&outsum[(size_t)g * 128 + c], acc);
}

__global__ void divide_k(const int* __restrict__ bounds, float* __restrict__ out) {
    int i = blockIdx.x * 256 + threadIdx.x;
    if (i < NG * 128) {
        int g = i >> 7;
        float c = (float)(bounds[g + 1] - bounds[g]);
        out[i] /= fmaxf(c, 1.f);
    }
}

extern "C" void kernel_launch(void* const* d_in, const int* in_sizes, int n_in,
                              void* d_out, int out_size, void* d_ws, size_t ws_size,
                              hipStream_t stream) {
    const float* x       = (const float*)d_in[0];
    const int*   ei      = (const int*)d_in[1];
    const int*   batch   = (const int*)d_in[2];
    const float* w_rel1  = (const float*)d_in[3];
    const float* b_rel1  = (const float*)d_in[4];
    const float* w_root1 = (const float*)d_in[5];
    const float* w_rel2  = (const float*)d_in[6];
    const float* b_rel2  = (const float*)d_in[7];
    const float* w_root2 = (const float*)d_in[8];
    const float* w_rel3  = (const float*)d_in[9];
    const float* b_rel3  = (const float*)d_in[10];
    const float* w_root3 = (const float*)d_in[11];
    const int* esrc = ei;
    const int* edst = ei + NE;

    unsigned short* Ab = (unsigned short*)d_ws;          // [NNP,128] agg out / y
    unsigned short* Bb = Ab + (size_t)NNP * 128;         // [NNP,128] h1 / r
    unsigned short* Cb = Bb + (size_t)NNP * 128;         // [NNP,256] h2 ; front = node vals
    unsigned short* xb = Cb + (size_t)NNP * 256;         // [NNP,128] x in bf16
    unsigned short* W1T = xb + (size_t)NNP * 128;        // [128,256]
    unsigned short* W2T = W1T + 128 * 256;               // [256,256]
    unsigned short* W3T = W2T + 256 * 256;               // [256,256]
    int* rowptr = (int*)(W3T + 256 * 256);               // NN+1
    int* colsrc = rowptr + (NN + 1);                     // NE
    int* tmp    = colsrc + NE;                           // NE
    int* H      = tmp + NE;                              // TOTH
    int* S      = H + TOTH;                              // TOTH
    int* hb     = S + TOTH;                              // 256
    int* hoff   = hb + 256;                              // 256
    int* bounds = hoff + 256;                            // NG+1
    float* outp = (float*)d_out;

    // --- setup (x->bf16 + weight transposes) and CSR build (split kernels) ---
    setup_k<<<(NN * 32 + 163840 + 255) / 256, 256, 0, stream>>>(
        x, w_rel1, w_root1, w_rel2, w_root2, w_rel3, w_root3, xb, W1T, W2T, W3T);
    hist_k<<<NBK, 256, 0, stream>>>(edst, H);
    hsum_k<<<NBH, 256, 0, stream>>>(H, hb);
    hscan_k<<<1, 256, 0, stream>>>(hb, hoff);
    happly_k<<<NBH, 256, 0, stream>>>(H, hoff, S);
    scatter_k<<<NBK, 256, 0, stream>>>(esrc, edst, S, tmp);
    csr_k<<<NBK, 256, 0, stream>>>(tmp, S, rowptr, colsrc);
    bounds_k<<<1, 128, 0, stream>>>(batch, bounds, outp);

    // L1: h1 = elu([agg(x) | x] @ W1 + b1)    -> Bb
    aggb_k<<<NN / 4, 256, 0, stream>>>(xb, rowptr, colsrc, Ab);
    gemm_k<64, 128, 128, true, true, true>
        <<<NNP / 64, 256, 0, stream>>>(Ab, xb, W1T, b_rel1, Bb);

    // L2: h2 = elu([agg(h1) | h1] @ W2 + b2)  -> Cb   (single-pass N=256)
    aggb_k<<<NN / 4, 256, 0, stream>>>(Bb, rowptr, colsrc, Ab);
    gemm256_k<128, true, true, true, false>
        <<<NNP / 64, 256, 0, stream>>>(Ab, Bb, W2T, b_rel2, Cb, nullptr);

    // L3: y = h2@w_rel3 -> Ab, r = h2@w_root3 -> Bb (one dispatch, split outputs)
    gemm256_k<256, false, false, false, true>
        <<<NNP / 64, 256, 0, stream>>>(Cb, nullptr, W3T, nullptr, Ab, Bb);

    // fused gather+elu per node, then segmented graph-mean
    aggf_k<<<NN / 4, 256, 0, stream>>>(Ab, Bb, b_rel3, rowptr, colsrc, Cb);
    sum_k<<<NN / 25, 128, 0, stream>>>(Cb, batch, outp);
    divide_k<<<(NG * 128 + 255) / 256, 256, 0, stream>>>(bounds, outp);
}

// Round 12
// 298.478 us; speedup vs baseline: 2.7708x; 1.0341x over previous
//
#include <hip/hip_runtime.h>
#include <math.h>

#define NN 50000
#define NNP 50048        // 391*128, padded row count for GEMM staging
#define NE 800000
#define NG 64
#define NBK 196          // buckets of 256 nodes
#define ECH 4082         // edges per hist/scatter block
#define TOTH (NBK * NBK) // 38416
#define NBH 151          // ceil(TOTH/256)
#define SBLK 6890        // setup blocks: (NN*32+163840)/256
#define SWORK (NN * 32 + 163840)

typedef __attribute__((ext_vector_type(8))) __bf16 bf16x8;
typedef __attribute__((ext_vector_type(4))) float f32x4;

__device__ inline unsigned short f2bf(float f) {
    unsigned int u = __float_as_uint(f);
    u += 0x7fffu + ((u >> 16) & 1u);   // round-to-nearest-even
    return (unsigned short)(u >> 16);
}
__device__ inline float bflo(unsigned int v) { return __uint_as_float(v << 16); }
__device__ inline float bfhi(unsigned int v) { return __uint_as_float(v & 0xffff0000u); }
__device__ inline float bfs(unsigned short v) { return __uint_as_float((unsigned int)v << 16); }

#define GLD_LDS16(g, l)                                                          \
    __builtin_amdgcn_global_load_lds(                                            \
        (const __attribute__((address_space(1))) unsigned int*)(g),              \
        (__attribute__((address_space(3))) unsigned int*)(l), 16, 0, 0)

// ------- front: x->bf16 + weight transposes + dst-histogram + bounds + out-zero ----
__global__ __launch_bounds__(256) void front_k(const float* __restrict__ x,
                                               const float* __restrict__ wr1,
                                               const float* __restrict__ wo1,
                                               const float* __restrict__ wr2,
                                               const float* __restrict__ wo2,
                                               const float* __restrict__ wr3,
                                               const float* __restrict__ wo3,
                                               const int* __restrict__ edst,
                                               const int* __restrict__ batch,
                                               unsigned short* __restrict__ xb,
                                               unsigned short* __restrict__ W1T,
                                               unsigned short* __restrict__ W2T,
                                               unsigned short* __restrict__ W3T,
                                               int* __restrict__ H,
                                               int* __restrict__ bounds,
                                               float* __restrict__ outp) {
    const int b = blockIdx.x, t = threadIdx.x;
    if (b < SBLK) {
        int id = b * 256 + t;
        if (id < NN * 32) {                       // x: 4 floats per thread
            float4 v = ((const float4*)x)[id];
            unsigned int p0 = ((unsigned int)f2bf(v.y) << 16) | f2bf(v.x);
            unsigned int p1 = ((unsigned int)f2bf(v.w) << 16) | f2bf(v.z);
            ((uint2*)xb)[id] = make_uint2(p0, p1);
            return;
        }
        int w = id - NN * 32;
        if (w < 32768) {
            int n = w >> 8, k = w & 255;
            W1T[w] = f2bf((k < 128) ? wr1[k * 128 + n] : wo1[(k - 128) * 128 + n]);
        } else if (w < 98304) {
            int j = w - 32768; int n = j >> 8, k = j & 255;
            W2T[j] = f2bf((k < 128) ? wr2[k * 256 + n] : wo2[(k - 128) * 256 + n]);
        } else if (w < 163840) {
            int j = w - 98304; int n = j >> 8, k = j & 255;
            W3T[j] = f2bf((n < 128) ? wr3[k * 128 + n] : wo3[k * 128 + (n - 128)]);
        }
        return;
    }
    if (b < SBLK + NBK) {                         // histogram chunk
        __shared__ int h[NBK];
        int k = b - SBLK;
        if (t < NBK) h[t] = 0;
        __syncthreads();
        int e0 = k * ECH, e1 = min(NE, e0 + ECH);
        for (int e = e0 + t; e < e1; e += 256) atomicAdd(&h[edst[e] >> 8], 1);
        __syncthreads();
        if (t < NBK) H[t * NBK + k] = h[t];       // bucket-major layout
        return;
    }
    // last block: graph bounds + zero output accumulator
    if (t <= NG) {
        int g = t, lo = 0, hi = NN;
        while (lo < hi) { int mid = (lo + hi) >> 1; if (batch[mid] < g) lo = mid + 1; else hi = mid; }
        bounds[g] = lo;
    }
    for (int i = t; i < NG * 128; i += 256) outp[i] = 0.f;
}

// ---------------- hierarchical scan of H ----------------
__global__ __launch_bounds__(256) void hsum_k(const int* __restrict__ H,
                                              int* __restrict__ hb) {
    int i = blockIdx.x * 256 + threadIdx.x;
    int v = (i < TOTH) ? H[i] : 0;
    for (int off = 32; off; off >>= 1) v += __shfl_xor(v, off, 64);
    __shared__ int ws[4];
    if ((threadIdx.x & 63) == 0) ws[threadIdx.x >> 6] = v;
    __syncthreads();
    if (threadIdx.x == 0) hb[blockIdx.x] = ws[0] + ws[1] + ws[2] + ws[3];
}

// folded: each block computes its own chunk offset (reduce hb[0..c)) + local scan
__global__ __launch_bounds__(256) void happly_k(const int* __restrict__ H,
                                                const int* __restrict__ hb,
                                                int* __restrict__ S) {
    __shared__ int s[256], ws[4], choff;
    const int t = threadIdx.x, c = blockIdx.x;
    {   // chunk offset = sum of hb[0..c)
        int v = (t < c) ? hb[t] : 0;              // c <= 150 < 256
        for (int off = 32; off; off >>= 1) v += __shfl_xor(v, off, 64);
        if ((t & 63) == 0) ws[t >> 6] = v;
        __syncthreads();
        if (t == 0) choff = ws[0] + ws[1] + ws[2] + ws[3];
        __syncthreads();
    }
    int i = c * 256 + t;
    int v = (i < TOTH) ? H[i] : 0;
    s[t] = v; __syncthreads();
    for (int off = 1; off < 256; off <<= 1) {
        int u = (t >= off) ? s[t - off] : 0;
        __syncthreads(); s[t] += u; __syncthreads();
    }
    if (i < TOTH) S[i] = choff + s[t] - v;
}

__global__ __launch_bounds__(256) void scatter_k(const int* __restrict__ src,
                                                 const int* __restrict__ dst,
                                                 const int* __restrict__ S,
                                                 int* __restrict__ tmp) {
    __shared__ int cur[NBK];
    int t = threadIdx.x, k = blockIdx.x;
    if (t < NBK) cur[t] = S[t * NBK + k];
    __syncthreads();
    int e0 = k * ECH, e1 = min(NE, e0 + ECH);
    for (int e = e0 + t; e < e1; e += 256) {
        int d = dst[e];
        int p = atomicAdd(&cur[d >> 8], 1);
        tmp[p] = ((d & 255) << 16) | src[e];
    }
}

__global__ __launch_bounds__(256) void csr_k(const int* __restrict__ tmp,
                                             const int* __restrict__ S,
                                             int* __restrict__ rowptr,
                                             int* __restrict__ colsrc) {
    __shared__ int hist[256], off[256], cur[256];
    int t = threadIdx.x, b = blockIdx.x;
    int base = S[b * NBK];
    int next = (b < NBK - 1) ? S[(b + 1) * NBK] : NE;
    int cntb = next - base;
    hist[t] = 0;
    __syncthreads();
    for (int i = t; i < cntb; i += 256) atomicAdd(&hist[tmp[base + i] >> 16], 1);
    __syncthreads();
    int v = hist[t];
    off[t] = v; __syncthreads();
    for (int o = 1; o < 256; o <<= 1) {
        int u = (t >= o) ? off[t - o] : 0;
        __syncthreads(); off[t] += u; __syncthreads();
    }
    int excl = off[t] - v;
    int node = b * 256 + t;
    if (node <= NN) rowptr[node] = base + excl;
    cur[t] = excl;
    __syncthreads();
    for (int i = t; i < cntb; i += 256) {
        int e = tmp[base + i];
        int p = atomicAdd(&cur[e >> 16], 1);
        colsrc[base + p] = e & 0xffff;
    }
}

// ---------------- edge aggregation, bf16 features, 8-way MLP ----------------
__global__ __launch_bounds__(256) void aggb_k(const unsigned short* __restrict__ feat,
                                              const int* __restrict__ rowptr,
                                              const int* __restrict__ colsrc,
                                              unsigned short* __restrict__ outp) {
    int node = __builtin_amdgcn_readfirstlane((int)(blockIdx.x * 4 + (threadIdx.x >> 6)));
    int lane = threadIdx.x & 63;
    int beg = rowptr[node], end = rowptr[node + 1];
    float ax = 0.f, ay = 0.f;
    int e = beg;
    for (; e + 8 <= end; e += 8) {
        unsigned int v[8];
#pragma unroll
        for (int i = 0; i < 8; ++i)
            v[i] = *(const unsigned int*)&feat[(size_t)colsrc[e + i] * 128 + lane * 2];
#pragma unroll
        for (int i = 0; i < 8; ++i) { ax += bflo(v[i]); ay += bfhi(v[i]); }
    }
    for (; e < end; ++e) {
        unsigned int v0 = *(const unsigned int*)&feat[(size_t)colsrc[e] * 128 + lane * 2];
        ax += bflo(v0); ay += bfhi(v0);
    }
    unsigned int p = ((unsigned int)f2bf(ay) << 16) | f2bf(ax);
    *(unsigned int*)&outp[(size_t)node * 128 + lane * 2] = p;
}

// fused L3 epilogue: v = elu(agg(y)[n] + r[n] + b3) per node (aggb structure)
__global__ __launch_bounds__(256) void aggf_k(const unsigned short* __restrict__ y,
                                              const unsigned short* __restrict__ rr,
                                              const float* __restrict__ b3,
                                              const int* __restrict__ rowptr,
                                              const int* __restrict__ colsrc,
                                              unsigned short* __restrict__ outp) {
    int node = __builtin_amdgcn_readfirstlane((int)(blockIdx.x * 4 + (threadIdx.x >> 6)));
    int lane = threadIdx.x & 63;
    int beg = rowptr[node], end = rowptr[node + 1];
    float ax = 0.f, ay = 0.f;
    int e = beg;
    for (; e + 8 <= end; e += 8) {
        unsigned int v[8];
#pragma unroll
        for (int i = 0; i < 8; ++i)
            v[i] = *(const unsigned int*)&y[(size_t)colsrc[e + i] * 128 + lane * 2];
#pragma unroll
        for (int i = 0; i < 8; ++i) { ax += bflo(v[i]); ay += bfhi(v[i]); }
    }
    for (; e < end; ++e) {
        unsigned int v0 = *(const unsigned int*)&y[(size_t)colsrc[e] * 128 + lane * 2];
        ax += bflo(v0); ay += bfhi(v0);
    }
    unsigned int rv = *(const unsigned int*)&rr[(size_t)node * 128 + lane * 2];
    float2 bb = *(const float2*)&b3[lane * 2];
    float vx = ax + bflo(rv) + bb.x;
    float vy = ay + bfhi(rv) + bb.y;
    vx = vx > 0.f ? vx : (__expf(vx) - 1.f);
    vy = vy > 0.f ? vy : (__expf(vy) - 1.f);
    unsigned int p = ((unsigned int)f2bf(vy) << 16) | f2bf(vx);
    *(unsigned int*)&outp[(size_t)node * 128 + lane * 2] = p;
}

// ---------------- 64x128 MFMA GEMM (L1) ----------------
template <int MT, int KA, int N, bool TWO, bool BIAS, bool ELU>
__global__ __launch_bounds__(256) void gemm_k(const unsigned short* __restrict__ A1,
                                              const unsigned short* __restrict__ A2,
                                              const unsigned short* __restrict__ WT,
                                              const float* __restrict__ bias,
                                              unsigned short* __restrict__ Cout) {
    constexpr int KTOT = TWO ? 2 * KA : KA;
    constexpr int MI = MT / 32;
    __shared__ __attribute__((aligned(16))) unsigned short As[MT * 32];
    __shared__ __attribute__((aligned(16))) unsigned short Bs[128 * 32];
    const int t = threadIdx.x;
    const int wv = t >> 6, lane = t & 63;
    const int qd = lane >> 4, l16 = lane & 15;
    const int m0 = blockIdx.x * MT, n0 = 0;
    const int mh = (wv & 1) * (MT / 2), nh = (wv >> 1) * 64;
    const int srow = lane >> 2;
    const int skk  = (lane & 3) * 8;

    f32x4 acc[MI][4] = {};

    for (int k0 = 0; k0 < KTOT; k0 += 32) {
        const unsigned short* Abase = (TWO && k0 >= KA) ? (A2 + (k0 - KA)) : (A1 + k0);
#pragma unroll
        for (int i = 0; i < MT / 64; ++i) {
            int chunk = wv * (MT / 64) + i;
            const unsigned short* g = Abase + (size_t)(m0 + chunk * 16 + srow) * KA + skk;
            GLD_LDS16(g, &As[chunk * 512]);
        }
        const unsigned short* Wbase = WT + k0;
#pragma unroll
        for (int i = 0; i < 2; ++i) {
            int chunk = wv * 2 + i;
            const unsigned short* g = Wbase + (size_t)(n0 + chunk * 16 + srow) * KTOT + skk;
            GLD_LDS16(g, &Bs[chunk * 512]);
        }
        __syncthreads();
        bf16x8 af[MI], bfr[4];
#pragma unroll
        for (int mi = 0; mi < MI; ++mi)
            af[mi] = *(const bf16x8*)&As[(mh + mi * 16 + l16) * 32 + qd * 8];
#pragma unroll
        for (int ni = 0; ni < 4; ++ni)
            bfr[ni] = *(const bf16x8*)&Bs[(nh + ni * 16 + l16) * 32 + qd * 8];
#pragma unroll
        for (int mi = 0; mi < MI; ++mi)
#pragma unroll
            for (int ni = 0; ni < 4; ++ni)
                acc[mi][ni] = __builtin_amdgcn_mfma_f32_16x16x32_bf16(
                    af[mi], bfr[ni], acc[mi][ni], 0, 0, 0);
        __syncthreads();
    }

#pragma unroll
    for (int mi = 0; mi < MI; ++mi)
#pragma unroll
        for (int ni = 0; ni < 4; ++ni)
#pragma unroll
            for (int r = 0; r < 4; ++r) {
                int mm = m0 + mh + mi * 16 + qd * 4 + r;
                if (mm < NN) {
                    int nn = n0 + nh + ni * 16 + l16;
                    float v = acc[mi][ni][r];
                    if (BIAS) v += bias[nn];
                    if (ELU) v = v > 0.f ? v : (__expf(v) - 1.f);
                    Cout[(size_t)mm * N + nn] = f2bf(v);
                }
            }
}

// ---------------- 64x256 single-pass GEMM (L2 / L3): A read once ----------------
template <int KA, bool TWO, bool BIAS, bool ELU, bool SPLIT>
__global__ __launch_bounds__(256) void gemm256_k(const unsigned short* __restrict__ A1,
                                                 const unsigned short* __restrict__ A2,
                                                 const unsigned short* __restrict__ WT,
                                                 const float* __restrict__ bias,
                                                 unsigned short* __restrict__ Cout,
                                                 unsigned short* __restrict__ Cout2) {
    constexpr int KTOT = TWO ? 2 * KA : KA;
    __shared__ __attribute__((aligned(16))) unsigned short As[64 * 32];
    __shared__ __attribute__((aligned(16))) unsigned short Bs[256 * 32];
    const int t = threadIdx.x;
    const int wv = t >> 6, lane = t & 63;
    const int qd = lane >> 4, l16 = lane & 15;
    const int m0 = blockIdx.x * 64;
    const int srow = lane >> 2;
    const int skk  = (lane & 3) * 8;

    f32x4 acc[4][4] = {};

    for (int k0 = 0; k0 < KTOT; k0 += 32) {
        const unsigned short* Abase = (TWO && k0 >= KA) ? (A2 + (k0 - KA)) : (A1 + k0);
        {
            const unsigned short* g = Abase + (size_t)(m0 + wv * 16 + srow) * KA + skk;
            GLD_LDS16(g, &As[wv * 512]);
        }
        const unsigned short* Wbase = WT + k0;
#pragma unroll
        for (int i = 0; i < 4; ++i) {
            int chunk = wv * 4 + i;
            const unsigned short* g = Wbase + (size_t)(chunk * 16 + srow) * KTOT + skk;
            GLD_LDS16(g, &Bs[chunk * 512]);
        }
        __syncthreads();
        bf16x8 af[4], bfr[4];
#pragma unroll
        for (int mi = 0; mi < 4; ++mi)
            af[mi] = *(const bf16x8*)&As[(mi * 16 + l16) * 32 + qd * 8];
#pragma unroll
        for (int ni = 0; ni < 4; ++ni)
            bfr[ni] = *(const bf16x8*)&Bs[(wv * 64 + ni * 16 + l16) * 32 + qd * 8];
#pragma unroll
        for (int mi = 0; mi < 4; ++mi)
#pragma unroll
            for (int ni = 0; ni < 4; ++ni)
                acc[mi][ni] = __builtin_amdgcn_mfma_f32_16x16x32_bf16(
                    af[mi], bfr[ni], acc[mi][ni], 0, 0, 0);
        __syncthreads();
    }

#pragma unroll
    for (int mi = 0; mi < 4; ++mi)
#pragma unroll
        for (int ni = 0; ni < 4; ++ni)
#pragma unroll
            for (int r = 0; r < 4; ++r) {
                int mm = m0 + mi * 16 + qd * 4 + r;
                if (mm < NN) {
                    int nn = wv * 64 + ni * 16 + l16;
                    float v = acc[mi][ni][r];
                    if (BIAS) v += bias[nn];
                    if (ELU) v = v > 0.f ? v : (__expf(v) - 1.f);
                    unsigned short b = f2bf(v);
                    if (SPLIT) {
                        unsigned short* dst = (nn < 128) ? Cout : Cout2;
                        dst[(size_t)mm * 128 + (nn & 127)] = b;
                    } else {
                        Cout[(size_t)mm * 256 + nn] = b;
                    }
                }
            }
}

// ---------------- segmented graph-sum + divide ----------------
__global__ __launch_bounds__(128) void sum_k(const unsigned short* __restrict__ vals,
                                             const int* __restrict__ batch,
                                             float* __restrict__ outsum) {
    const int CH = 25;                        // 2000 * 25 = 50000
    int n0 = blockIdx.x * CH;
    int c = threadIdx.x;
    int g = batch[n0];
    float acc = 0.f;
    for (int i = 0; i < CH; ++i) {
        int n = n0 + i;
        int gn = batch[n];
        if (gn != g) {
            unsafeAtomicAdd(&outsum[(size_t)g * 128 + c], acc);
            acc = 0.f; g = gn;
        }
        acc += bfs(vals[(size_t)n * 128 + c]);
    }
    unsafeAtomicAdd(&outsum[(size_t)g * 128 + c], acc);
}

__global__ void divide_k(const int* __restrict__ bounds, float* __restrict__ out) {
    int i = blockIdx.x * 256 + threadIdx.x;
    if (i < NG * 128) {
        int g = i >> 7;
        float c = (float)(bounds[g + 1] - bounds[g]);
        out[i] /= fmaxf(c, 1.f);
    }
}

extern "C" void kernel_launch(void* const* d_in, const int* in_sizes, int n_in,
                              void* d_out, int out_size, void* d_ws, size_t ws_size,
                              hipStream_t stream) {
    const float* x       = (const float*)d_in[0];
    const int*   ei      = (const int*)d_in[1];
    const int*   batch   = (const int*)d_in[2];
    const float* w_rel1  = (const float*)d_in[3];
    const float* b_rel1  = (const float*)d_in[4];
    const float* w_root1 = (const float*)d_in[5];
    const float* w_rel2  = (const float*)d_in[6];
    const float* b_rel2  = (const float*)d_in[7];
    const float* w_root2 = (const float*)d_in[8];
    const float* w_rel3  = (const float*)d_in[9];
    const float* b_rel3  = (const float*)d_in[10];
    const float* w_root3 = (const float*)d_in[11];
    const int* esrc = ei;
    const int* edst = ei + NE;

    unsigned short* Ab = (unsigned short*)d_ws;          // [NNP,128] agg out / y
    unsigned short* Bb = Ab + (size_t)NNP * 128;         // [NNP,128] h1 / r
    unsigned short* Cb = Bb + (size_t)NNP * 128;         // [NNP,256] h2 ; front = node vals
    unsigned short* xb = Cb + (size_t)NNP * 256;         // [NNP,128] x in bf16
    unsigned short* W1T = xb + (size_t)NNP * 128;        // [128,256]
    unsigned short* W2T = W1T + 128 * 256;               // [256,256]
    unsigned short* W3T = W2T + 256 * 256;               // [256,256]
    int* rowptr = (int*)(W3T + 256 * 256);               // NN+1
    int* colsrc = rowptr + (NN + 1);                     // NE
    int* tmp    = colsrc + NE;                           // NE
    int* H      = tmp + NE;                              // TOTH
    int* S      = H + TOTH;                              // TOTH
    int* hb     = S + TOTH;                              // 256
    int* bounds = hb + 256;                              // NG+1
    float* outp = (float*)d_out;

    // --- front (setup + hist + bounds/zero in one dispatch), then scan chain ---
    front_k<<<SBLK + NBK + 1, 256, 0, stream>>>(
        x, w_rel1, w_root1, w_rel2, w_root2, w_rel3, w_root3, edst, batch,
        xb, W1T, W2T, W3T, H, bounds, outp);
    hsum_k<<<NBH, 256, 0, stream>>>(H, hb);
    happly_k<<<NBH, 256, 0, stream>>>(H, hb, S);
    scatter_k<<<NBK, 256, 0, stream>>>(esrc, edst, S, tmp);
    csr_k<<<NBK, 256, 0, stream>>>(tmp, S, rowptr, colsrc);

    // L1: h1 = elu([agg(x) | x] @ W1 + b1)    -> Bb
    aggb_k<<<NN / 4, 256, 0, stream>>>(xb, rowptr, colsrc, Ab);
    gemm_k<64, 128, 128, true, true, true>
        <<<NNP / 64, 256, 0, stream>>>(Ab, xb, W1T, b_rel1, Bb);

    // L2: h2 = elu([agg(h1) | h1] @ W2 + b2)  -> Cb   (single-pass N=256)
    aggb_k<<<NN / 4, 256, 0, stream>>>(Bb, rowptr, colsrc, Ab);
    gemm256_k<128, true, true, true, false>
        <<<NNP / 64, 256, 0, stream>>>(Ab, Bb, W2T, b_rel2, Cb, nullptr);

    // L3: y = h2@w_rel3 -> Ab, r = h2@w_root3 -> Bb (one dispatch, split outputs)
    gemm256_k<256, false, false, false, true>
        <<<NNP / 64, 256, 0, stream>>>(Cb, nullptr, W3T, nullptr, Ab, Bb);

    // fused gather+elu per node, then segmented graph-mean
    aggf_k<<<NN / 4, 256, 0, stream>>>(Ab, Bb, b_rel3, rowptr, colsrc, Cb);
    sum_k<<<NN / 25, 128, 0, stream>>>(Cb, batch, outp);
    divide_k<<<(NG * 128 + 255) / 256, 256, 0, stream>>>(bounds, outp);
}